// Round 13
// baseline (853.274 us; speedup 1.0000x reference)
//
#include <hip/hip_runtime.h>
#include <hip/hip_bf16.h>
#include <hip/hip_cooperative_groups.h>
#include <math.h>

namespace cg = cooperative_groups;

// ---------------- problem constants ----------------
#define NNODES  10000
#define NEDGES  80000
#define NTOT    90000          // edges + self loops
#define IN_DIM  512
#define H1_DIM  4096
#define H2_DIM  1024
#define ODIM    7
#define MAXDEG  128
#define NEG_SLOPE 0.2f
#define MROWS   10240          // padded M for dot-partial buffers (80 row-panels * 128)
#define NBX1    (H1_DIM / 128) // 32 column blocks in GEMM1
#define COOPB   1024           // cooperative grid size (4 blocks/CU -- safely co-resident)

typedef __hip_bfloat16 bf16;
typedef __attribute__((ext_vector_type(8))) short short8;
typedef __attribute__((ext_vector_type(4))) float f32x4;

__device__ inline void unpack_bf2(unsigned u, float& lo, float& hi) {
    union { unsigned i; float f; } a, b;
    a.i = u << 16; b.i = u & 0xffff0000u;
    lo = a.f; hi = b.f;
}

// async global->LDS, 16B per lane; lds ptr must be wave-uniform base (lane*16 added by HW)
#define ASYNC_COPY16(lds, g)                                                              \
    __builtin_amdgcn_global_load_lds((const __attribute__((address_space(1))) void*)(g),  \
                                     (__attribute__((address_space(3))) void*)(lds),      \
                                     16, 0, 0)

// ---------------- merged prep: W1/W2 transpose+fold + bucket build in one launch ----------------
__global__ __launch_bounds__(256) void prep_all(const float* __restrict__ W1,
                                                bf16* __restrict__ W1T,
                                                const float* __restrict__ as1,
                                                const float* __restrict__ ad1,
                                                float* __restrict__ w1s,
                                                float* __restrict__ w1d,
                                                const float* __restrict__ W2,
                                                bf16* __restrict__ W2T,
                                                const float* __restrict__ as2,
                                                const float* __restrict__ ad2,
                                                float* __restrict__ w2s,
                                                float* __restrict__ w2d,
                                                const int* __restrict__ ei,
                                                int* cnt, int* bucket) {
    const int nb1 = (H1_DIM / 32) * (IN_DIM / 32);   // 2048
    const int nb2 = (H2_DIM / 32) * (H1_DIM / 32);   // 4096
    int bid = blockIdx.x;

    if (bid >= nb1 + nb2) {                          // bucket blocks
        int k = (bid - nb1 - nb2) * 256 + threadIdx.x;
        if (k < NTOT) {
            int s, d;
            if (k < NEDGES) { s = ei[k]; d = ei[NEDGES + k]; }
            else            { s = k - NEDGES; d = s; }
            int pos = atomicAdd(&cnt[d], 1);
            if (pos < MAXDEG) bucket[d * MAXDEG + pos] = s;
        }
        return;
    }

    const float *W, *a_s, *a_d; bf16 *WT; float *w_s, *w_d; int R, C, cblocks;
    if (bid < nb1) { W = W1; WT = W1T; a_s = as1; a_d = ad1; w_s = w1s; w_d = w1d;
                     R = IN_DIM; C = H1_DIM; cblocks = H1_DIM / 32; }
    else { bid -= nb1; W = W2; WT = W2T; a_s = as2; a_d = ad2; w_s = w2s; w_d = w2d;
           R = H1_DIM; C = H2_DIM; cblocks = H2_DIM / 32; }
    int c0 = (bid % cblocks) * 32, r0 = (bid / cblocks) * 32;

    __shared__ float t[32][33];
    int x = threadIdx.x & 31, y = threadIdx.x >> 5;   // 32 x 8
    float asv = a_s[c0 + x], adv = a_d[c0 + x];
    #pragma unroll
    for (int dy = 0; dy < 32; dy += 8) {
        float w = W[(size_t)(r0 + y + dy) * C + c0 + x];
        t[y + dy][x] = w;
        float ps = w * asv, pd = w * adv;
        #pragma unroll
        for (int off = 16; off > 0; off >>= 1) {
            ps += __shfl_down(ps, off, 32);
            pd += __shfl_down(pd, off, 32);
        }
        if (x == 0) {
            atomicAdd(&w_s[r0 + y + dy], ps);
            atomicAdd(&w_d[r0 + y + dy], pd);
        }
    }
    __syncthreads();
    #pragma unroll
    for (int dy = 0; dy < 32; dy += 8)
        WT[(size_t)(c0 + y + dy) * R + r0 + x] = __float2bfloat16(t[x][y + dy]);
}

// ---------------- cooperative layer-1: [dots+cvt] -> grid.sync -> [aggregate gather] ----------------
__global__ __launch_bounds__(128) void layer1_coop(const float* __restrict__ X,
                                                   const float* __restrict__ w_s,
                                                   const float* __restrict__ w_d,
                                                   float* __restrict__ s_src,
                                                   float* __restrict__ s_dst,
                                                   bf16* __restrict__ XB,
                                                   const int* __restrict__ bucket,
                                                   const int* __restrict__ cnt,
                                                   bf16* __restrict__ OUT) {
    cg::grid_group grid = cg::this_grid();
    __shared__ float red[2][2];
    __shared__ float alpha[MAXDEG];
    __shared__ int   ssrc[MAXDEG];
    const int t = threadIdx.x;
    const int wave = t >> 6;

    // phase 1: per-node dots on x (fp32 exact) + bf16 conversion (single x read)
    for (int n = blockIdx.x; n < NNODES; n += gridDim.x) {
        float4 xv = ((const float4*)(X + (size_t)n * IN_DIM))[t];
        float4 wsv = ((const float4*)w_s)[t];
        float4 wdv = ((const float4*)w_d)[t];
        bf16 o[4] = { __float2bfloat16(xv.x), __float2bfloat16(xv.y),
                      __float2bfloat16(xv.z), __float2bfloat16(xv.w) };
        *(uint2*)(XB + (size_t)n * IN_DIM + 4 * t) = *(uint2*)o;
        float ss = xv.x*wsv.x + xv.y*wsv.y + xv.z*wsv.z + xv.w*wsv.w;
        float sd = xv.x*wdv.x + xv.y*wdv.y + xv.z*wdv.z + xv.w*wdv.w;
        #pragma unroll
        for (int off = 32; off > 0; off >>= 1) {
            ss += __shfl_down(ss, off);
            sd += __shfl_down(sd, off);
        }
        if ((t & 63) == 0) { red[0][wave] = ss; red[1][wave] = sd; }
        __syncthreads();
        if (t == 0) {
            s_src[n] = red[0][0] + red[0][1];
            s_dst[n] = red[1][0] + red[1][1];
        }
        __syncthreads();   // protect red for next iteration
    }

    __threadfence();       // agent-scope: make s_src/XB visible across XCDs
    grid.sync();

    // phase 2: segment softmax + weighted gather of XB -> OUT (bf16)
    for (int n = blockIdx.x; n < NNODES; n += gridDim.x) {
        int c = min(cnt[n], MAXDEG);
        if (t < c) {
            int s = bucket[n * MAXDEG + t];
            ssrc[t] = s;
            float e = s_src[s] + s_dst[n];
            alpha[t] = (e > 0.f) ? e : NEG_SLOPE * e;
        }
        __syncthreads();
        if (t == 0) {
            float m = -1e30f;
            for (int j = 0; j < c; ++j) m = fmaxf(m, alpha[j]);
            float s = 0.f;
            for (int j = 0; j < c; ++j) { float ex = __expf(alpha[j] - m); alpha[j] = ex; s += ex; }
            float inv = 1.f / s;
            for (int j = 0; j < c; ++j) alpha[j] *= inv;
        }
        __syncthreads();
        float acc[4] = {};
        for (int j = 0; j < c; ++j) {
            float a = alpha[j];
            uint2 raw = ((const uint2*)(XB + (size_t)ssrc[j] * IN_DIM))[t];
            float f0, f1, f2, f3;
            unpack_bf2(raw.x, f0, f1); unpack_bf2(raw.y, f2, f3);
            acc[0] = fmaf(a, f0, acc[0]); acc[1] = fmaf(a, f1, acc[1]);
            acc[2] = fmaf(a, f2, acc[2]); acc[3] = fmaf(a, f3, acc[3]);
        }
        bf16 o[4] = { __float2bfloat16(acc[0]), __float2bfloat16(acc[1]),
                      __float2bfloat16(acc[2]), __float2bfloat16(acc[3]) };
        *(uint2*)(OUT + (size_t)n * IN_DIM + 4 * t) = *(uint2*)o;
        __syncthreads();   // protect alpha/ssrc for next iteration
    }
}

// ---------------- bf16 MFMA GEMM (gemm_bt): C[M,N] = A[M,K] @ BT[N,K]^T ----------------
// 16x16x32 fragments. TM=TN=128, 4 waves. XCD-affine block swizzle (R7). XOR k-chunk swizzle.
// PIPE=false: 2-barrier BK=64 (short K, R8); PIPE=true: single-barrier BK=32 dbuf (long K, R8).
// FUSEDOTS: dot partials in LDS -> one coalesced store per row into [NBX1][MROWS] partials.
template<bool BIASRELU, bool FUSEDOTS, bool PIPE>
__global__ __launch_bounds__(256) void gemm_mfma(const bf16* __restrict__ A,
                                                 const bf16* __restrict__ BT,
                                                 const float* __restrict__ bias,
                                                 const float* __restrict__ w_s,
                                                 const float* __restrict__ w_d,
                                                 float* __restrict__ s_src,
                                                 float* __restrict__ s_dst,
                                                 bf16* __restrict__ C,
                                                 int M, int N, int K) {
    constexpr int TM = 128, TN = 128, NI = 4, NJ = 4;
    __shared__ alignas(16) bf16 As[2][TM][32];
    __shared__ alignas(16) bf16 Bs[2][TN][32];
    __shared__ float pd_s[FUSEDOTS ? TM : 1];
    __shared__ float pd_d[FUSEDOTS ? TM : 1];
    const int tid  = threadIdx.x;
    const int wave = tid >> 6;
    const int lane = tid & 63;

    const int gx = gridDim.x;
    const int j  = blockIdx.y * gx + blockIdx.x;
    const int band = j / (8 * gx);
    const int r8   = j - band * (8 * gx);
    const int by = (r8 & 7) + 8 * band;
    const int bx = r8 >> 3;
    const int row0 = by * TM;
    const int col0 = bx * TN;
    if (row0 >= M) return;

    if constexpr (FUSEDOTS) {
        if (tid < TM) { pd_s[tid] = 0.f; pd_d[tid] = 0.f; }
    }

    const int wr0 = (wave >> 1) * 64;
    const int wc0 = (wave & 1) * 64;

    const int srow  = tid >> 2;
    const int skoff = ((tid & 3) ^ (srow & 3)) * 8;
    const bf16* a0 = A + (size_t)min(row0 + srow, M - 1) * K + skoff;
    const bf16* a1 = A + (size_t)min(row0 + 64 + srow, M - 1) * K + skoff;
    const bf16* b0 = BT + (size_t)(col0 + srow) * K + skoff;
    const bf16* b1 = BT + (size_t)(col0 + 64 + srow) * K + skoff;

    f32x4 acc[NI][NJ] = {};
    const int fRow  = lane & 15;
    const int fKoff = ((lane >> 4) ^ (fRow & 3)) * 8;

    if constexpr (PIPE) {
        const int NIT = K >> 5;
        ASYNC_COPY16(&As[0][wave * 16][0],      a0);
        ASYNC_COPY16(&As[0][64 + wave * 16][0], a1);
        ASYNC_COPY16(&Bs[0][wave * 16][0],      b0);
        ASYNC_COPY16(&Bs[0][64 + wave * 16][0], b1);
        __syncthreads();
        for (int it = 0; it < NIT; ++it) {
            const int cb = it & 1, nb = cb ^ 1;
            if (it + 1 < NIT) {
                const int ko = (it + 1) << 5;
                ASYNC_COPY16(&As[nb][wave * 16][0],      a0 + ko);
                ASYNC_COPY16(&As[nb][64 + wave * 16][0], a1 + ko);
                ASYNC_COPY16(&Bs[nb][wave * 16][0],      b0 + ko);
                ASYNC_COPY16(&Bs[nb][64 + wave * 16][0], b1 + ko);
            }
            short8 af[NI], bfr[NJ];
            #pragma unroll
            for (int i = 0; i < NI; ++i)
                af[i] = *(const short8*)&As[cb][wr0 + i * 16 + fRow][fKoff];
            #pragma unroll
            for (int jj = 0; jj < NJ; ++jj)
                bfr[jj] = *(const short8*)&Bs[cb][wc0 + jj * 16 + fRow][fKoff];
            #pragma unroll
            for (int i = 0; i < NI; ++i)
                #pragma unroll
                for (int jj = 0; jj < NJ; ++jj)
                    acc[i][jj] = __builtin_amdgcn_mfma_f32_16x16x32_bf16(af[i], bfr[jj], acc[i][jj], 0, 0, 0);
            __syncthreads();
        }
    } else {
        for (int k0 = 0; k0 < K; k0 += 64) {
            #pragma unroll
            for (int h = 0; h < 2; ++h) {
                ASYNC_COPY16(&As[h][wave * 16][0],      a0 + k0 + h * 32);
                ASYNC_COPY16(&As[h][64 + wave * 16][0], a1 + k0 + h * 32);
                ASYNC_COPY16(&Bs[h][wave * 16][0],      b0 + k0 + h * 32);
                ASYNC_COPY16(&Bs[h][64 + wave * 16][0], b1 + k0 + h * 32);
            }
            __syncthreads();
            #pragma unroll
            for (int h = 0; h < 2; ++h) {
                short8 af[NI], bfr[NJ];
                #pragma unroll
                for (int i = 0; i < NI; ++i)
                    af[i] = *(const short8*)&As[h][wr0 + i * 16 + fRow][fKoff];
                #pragma unroll
                for (int jj = 0; jj < NJ; ++jj)
                    bfr[jj] = *(const short8*)&Bs[h][wc0 + jj * 16 + fRow][fKoff];
                #pragma unroll
                for (int i = 0; i < NI; ++i)
                    #pragma unroll
                    for (int jj = 0; jj < NJ; ++jj)
                        acc[i][jj] = __builtin_amdgcn_mfma_f32_16x16x32_bf16(af[i], bfr[jj], acc[i][jj], 0, 0, 0);
            }
            __syncthreads();
        }
    }

    // epilogue: C/D layout col=lane&15, row=(lane>>4)*4+reg [m89/m91]
    const int crow = (lane >> 4) * 4;
    const int ccol = lane & 15;
    #pragma unroll
    for (int i = 0; i < NI; ++i) {
        #pragma unroll
        for (int r = 0; r < 4; ++r) {
            int gm = row0 + wr0 + i * 16 + crow + r;
            float vss = 0.f, vsd = 0.f;
            if (gm < M) {
                #pragma unroll
                for (int jj = 0; jj < NJ; ++jj) {
                    int gn = col0 + wc0 + jj * 16 + ccol;
                    float v = acc[i][jj][r];
                    if (BIASRELU) v = fmaxf(v + bias[gn], 0.f);
                    C[(size_t)gm * N + gn] = __float2bfloat16(v);
                    if (FUSEDOTS) {
                        vss = fmaf(v, w_s[gn], vss);
                        vsd = fmaf(v, w_d[gn], vsd);
                    }
                }
            }
            if (FUSEDOTS) {
                #pragma unroll
                for (int m2 = 1; m2 < 16; m2 <<= 1) {
                    vss += __shfl_xor(vss, m2, 16);
                    vsd += __shfl_xor(vsd, m2, 16);
                }
                if ((lane & 15) == 0) {
                    atomicAdd(&pd_s[wr0 + i * 16 + crow + r], vss);   // LDS atomic (cheap)
                    atomicAdd(&pd_d[wr0 + i * 16 + crow + r], vsd);
                }
            }
        }
    }
    if constexpr (FUSEDOTS) {
        __syncthreads();
        if (tid < TM) {
            s_src[(size_t)bx * MROWS + row0 + tid] = pd_s[tid];
            s_dst[(size_t)bx * MROWS + row0 + tid] = pd_d[tid];
        }
    }
}

// ---------------- cooperative layer-2/3 tail ----------------
// phase 0: reduce dot partials -> s_src/s_dst; phase 1: agg2 (+bias+relu) fused with
// layer-3 projection + dots; phase 2: aggregate3 + bias + log_softmax.
__global__ __launch_bounds__(128) void layer3_coop(const float* __restrict__ pds,
                                                   const float* __restrict__ pdd,
                                                   float* __restrict__ s_src,
                                                   float* __restrict__ s_dst,
                                                   const bf16* __restrict__ H,
                                                   const int* __restrict__ bucket,
                                                   const int* __restrict__ cnt,
                                                   const float* __restrict__ bias,
                                                   const float* __restrict__ W3,
                                                   const float* __restrict__ as3,
                                                   const float* __restrict__ ad3,
                                                   float* __restrict__ H3,
                                                   float* __restrict__ s3_src,
                                                   float* __restrict__ s3_dst,
                                                   const float* __restrict__ b3,
                                                   float* __restrict__ out) {
    cg::grid_group grid = cg::this_grid();
    __shared__ float alpha[MAXDEG];
    __shared__ int   ssrc[MAXDEG];
    __shared__ float red[2][ODIM];
    __shared__ float ovec[ODIM];
    const int t = threadIdx.x;
    const int wave = t >> 6;

    // phase 0: reduce per-column-block partials
    for (int g = blockIdx.x * 128 + t; g < NNODES; g += gridDim.x * 128) {
        float s = 0.f, d = 0.f;
        #pragma unroll
        for (int b = 0; b < NBX1; ++b) {
            s += pds[(size_t)b * MROWS + g];
            d += pdd[(size_t)b * MROWS + g];
        }
        s_src[g] = s; s_dst[g] = d;
    }
    __threadfence();
    grid.sync();

    // phase 1: aggregate h2 (+bias+relu), fused layer-3 projection + dots
    for (int n = blockIdx.x; n < NNODES; n += gridDim.x) {
        int c = min(cnt[n], MAXDEG);
        if (t < c) {
            int s = bucket[n * MAXDEG + t];
            ssrc[t] = s;
            float e = s_src[s] + s_dst[n];
            alpha[t] = (e > 0.f) ? e : NEG_SLOPE * e;
        }
        __syncthreads();
        if (t == 0) {
            float m = -1e30f;
            for (int j = 0; j < c; ++j) m = fmaxf(m, alpha[j]);
            float s = 0.f;
            for (int j = 0; j < c; ++j) { float ex = __expf(alpha[j] - m); alpha[j] = ex; s += ex; }
            float inv = 1.f / s;
            for (int j = 0; j < c; ++j) alpha[j] *= inv;
        }
        __syncthreads();
        float acc[8] = {};
        for (int j = 0; j < c; ++j) {
            float a = alpha[j];
            uint4 raw = ((const uint4*)(H + (size_t)ssrc[j] * H2_DIM))[t];
            float f0, f1, f2, f3, f4, f5, f6, f7;
            unpack_bf2(raw.x, f0, f1); unpack_bf2(raw.y, f2, f3);
            unpack_bf2(raw.z, f4, f5); unpack_bf2(raw.w, f6, f7);
            acc[0] = fmaf(a, f0, acc[0]); acc[1] = fmaf(a, f1, acc[1]);
            acc[2] = fmaf(a, f2, acc[2]); acc[3] = fmaf(a, f3, acc[3]);
            acc[4] = fmaf(a, f4, acc[4]); acc[5] = fmaf(a, f5, acc[5]);
            acc[6] = fmaf(a, f6, acc[6]); acc[7] = fmaf(a, f7, acc[7]);
        }
        float p[ODIM] = {};
        #pragma unroll
        for (int k = 0; k < 8; ++k) {
            float v = fmaxf(acc[k] + bias[8 * t + k], 0.f);
            const float* wrow = W3 + (size_t)(8 * t + k) * ODIM;
            #pragma unroll
            for (int o = 0; o < ODIM; ++o)
                p[o] = fmaf(v, wrow[o], p[o]);
        }
        #pragma unroll
        for (int o = 0; o < ODIM; ++o)
            #pragma unroll
            for (int off = 32; off > 0; off >>= 1)
                p[o] += __shfl_down(p[o], off);
        if ((t & 63) == 0)
            #pragma unroll
            for (int o = 0; o < ODIM; ++o) red[wave][o] = p[o];
        __syncthreads();
        if (t == 0) {
            float ss = 0.f, sd = 0.f;
            #pragma unroll
            for (int o = 0; o < ODIM; ++o) {
                float v = red[0][o] + red[1][o];
                H3[n * ODIM + o] = v;
                ss = fmaf(v, as3[o], ss);
                sd = fmaf(v, ad3[o], sd);
            }
            s3_src[n] = ss; s3_dst[n] = sd;
        }
        __syncthreads();   // protect alpha/ssrc/red for next iteration
    }
    __threadfence();
    grid.sync();

    // phase 2: layer-3 aggregate + bias + log_softmax
    for (int n = blockIdx.x; n < NNODES; n += gridDim.x) {
        int c = min(cnt[n], MAXDEG);
        if (t < c) {
            int s = bucket[n * MAXDEG + t];
            ssrc[t] = s;
            float e = s3_src[s] + s3_dst[n];
            alpha[t] = (e > 0.f) ? e : NEG_SLOPE * e;
        }
        __syncthreads();
        if (t == 0) {
            float m = -1e30f;
            for (int j = 0; j < c; ++j) m = fmaxf(m, alpha[j]);
            float s = 0.f;
            for (int j = 0; j < c; ++j) { float ex = __expf(alpha[j] - m); alpha[j] = ex; s += ex; }
            float inv = 1.f / s;
            for (int j = 0; j < c; ++j) alpha[j] *= inv;
        }
        __syncthreads();
        if (t < ODIM) {
            float acc = 0.f;
            for (int j = 0; j < c; ++j)
                acc = fmaf(alpha[j], H3[ssrc[j] * ODIM + t], acc);
            ovec[t] = acc + b3[t];
        }
        __syncthreads();
        if (t == 0) {
            float m = ovec[0];
            for (int k = 1; k < ODIM; ++k) m = fmaxf(m, ovec[k]);
            float s = 0.f;
            for (int k = 0; k < ODIM; ++k) s += __expf(ovec[k] - m);
            float lse = m + logf(s);
            for (int k = 0; k < ODIM; ++k) out[n * ODIM + k] = ovec[k] - lse;
        }
        __syncthreads();   // protect shared state for next iteration
    }
}

// ---------------- host launch ----------------
extern "C" void kernel_launch(void* const* d_in, const int* in_sizes, int n_in,
                              void* d_out, int out_size, void* d_ws, size_t ws_size,
                              hipStream_t stream) {
    const float* x   = (const float*)d_in[0];
    const int*   ei  = (const int*)  d_in[1];
    const float* W1  = (const float*)d_in[2];
    const float* as1 = (const float*)d_in[3];
    const float* ad1 = (const float*)d_in[4];
    const float* b1  = (const float*)d_in[5];
    const float* W2  = (const float*)d_in[6];
    const float* as2 = (const float*)d_in[7];
    const float* ad2 = (const float*)d_in[8];
    const float* b2  = (const float*)d_in[9];
    const float* W3  = (const float*)d_in[10];
    const float* as3 = (const float*)d_in[11];
    const float* ad3 = (const float*)d_in[12];
    const float* b3  = (const float*)d_in[13];
    float* outp = (float*)d_out;

    // workspace layout with aliasing (~140 MB)
    char* p = (char*)d_ws;
    bf16*  x2     = (bf16*)p;   p += (size_t)NNODES * H1_DIM * sizeof(bf16);   // 81.92 MB
    bf16*  r2     = (bf16*)p;   p += (size_t)NNODES * H2_DIM * sizeof(bf16);   // 20.48 MB
    bf16*  r3     = (bf16*)p;   p += (size_t)NNODES * H2_DIM * sizeof(bf16);   // 20.48 MB
    bf16*  W2T    = (bf16*)p;   p += (size_t)H2_DIM * H1_DIM * sizeof(bf16);   // 8.39 MB
    float* pds    = (float*)p;  p += (size_t)NBX1 * MROWS * sizeof(float);     // 1.31 MB
    float* pdd    = (float*)p;  p += (size_t)NBX1 * MROWS * sizeof(float);     // 1.31 MB
    float* h3     = (float*)p;  p += (size_t)NNODES * ODIM * sizeof(float);
    float* ssrc   = (float*)p;  p += NNODES * sizeof(float);
    float* sdst   = (float*)p;  p += NNODES * sizeof(float);
    float* ssrc3  = (float*)p;  p += NNODES * sizeof(float);
    float* sdst3  = (float*)p;  p += NNODES * sizeof(float);
    float* w1s    = (float*)p;  p += IN_DIM * sizeof(float);                   // w-group contiguous:
    float* w1d    = (float*)p;  p += IN_DIM * sizeof(float);                   //   one memset below
    float* w2s    = (float*)p;  p += H1_DIM * sizeof(float);
    float* w2d    = (float*)p;  p += H1_DIM * sizeof(float);
    int*   cnt    = (int*)p;    p += NNODES * sizeof(int);
    int*   bucket = (int*)p;    p += (size_t)NNODES * MAXDEG * sizeof(int);    // 5.12 MB
    size_t required = (size_t)(p - (char*)d_ws);
    if (ws_size < required) return;

    bf16* xb    = x2;              // [10000][512] bf16 copy of x (dead before GEMM1 writes x2)
    bf16* aggxb = r2;              // [10000][512]  (dead after GEMM1)
    bf16* h2    = r2;              // [10000][1024] (written by GEMM2)
    bf16* W1T   = r3;              // [4096][512]   (dead after GEMM1)

    hipMemsetAsync(cnt, 0, NNODES * sizeof(int), stream);
    hipMemsetAsync(w1s, 0, (2 * IN_DIM + 2 * H1_DIM) * sizeof(float), stream);  // w1s..w2d

    // ---- merged prep: both transposes + attention folds + edge bucketing (one launch) ----
    {
        int nb1 = (H1_DIM / 32) * (IN_DIM / 32);     // 2048
        int nb2 = (H2_DIM / 32) * (H1_DIM / 32);     // 4096
        int nbB = (NTOT + 255) / 256;                // 352
        prep_all<<<nb1 + nb2 + nbB, 256, 0, stream>>>(W1, W1T, as1, ad1, w1s, w1d,
                                                      W2, W2T, as2, ad2, w2s, w2d,
                                                      ei, cnt, bucket);
    }

    // ---- cooperative layer 1: dots+cvt -> grid.sync -> gather aggregate ----
    {
        void* args[] = { (void*)&x, (void*)&w1s, (void*)&w1d, (void*)&ssrc, (void*)&sdst,
                         (void*)&xb, (void*)&bucket, (void*)&cnt, (void*)&aggxb };
        hipLaunchCooperativeKernel((void*)layer1_coop, dim3(COOPB), dim3(128), args, 0, stream);
    }

    // padded row-panel count (multiple of 8 for the XCD swizzle)
    const int nRowPad = ((((NNODES + 127) / 128) + 7) / 8) * 8;   // 80

    // ---- GEMM1 (+bias+relu) with fused layer-2 dot partials: 2-barrier BK=64 (short K) ----
    {
        dim3 g(H1_DIM / 128, nRowPad);
        gemm_mfma<true, true, false><<<g, 256, 0, stream>>>(aggxb, W1T, b1, w2s, w2d,
                                                            pds, pdd, x2, NNODES, H1_DIM, IN_DIM);
    }

    // ---- GEMM2: single-barrier BK=32 dbuf (long K) ----
    {
        dim3 g(H2_DIM / 128, nRowPad);
        gemm_mfma<false, false, true><<<g, 256, 0, stream>>>(x2, W2T, nullptr, nullptr, nullptr,
                                                             nullptr, nullptr, h2, NNODES, H2_DIM, H1_DIM);
    }

    // ---- cooperative tail: reduce dots -> agg2+proj3+dots -> aggregate3+log_softmax ----
    {
        void* args[] = { (void*)&pds, (void*)&pdd, (void*)&ssrc, (void*)&sdst, (void*)&h2,
                         (void*)&bucket, (void*)&cnt, (void*)&b2, (void*)&W3, (void*)&as3,
                         (void*)&ad3, (void*)&h3, (void*)&ssrc3, (void*)&sdst3, (void*)&b3,
                         (void*)&outp };
        hipLaunchCooperativeKernel((void*)layer3_coop, dim3(COOPB), dim3(128), args, 0, stream);
    }
}

// Round 14
// 422.083 us; speedup vs baseline: 2.0216x; 2.0216x over previous
//
#include <hip/hip_runtime.h>
#include <hip/hip_bf16.h>
#include <math.h>

// ---------------- problem constants ----------------
#define NNODES  10000
#define NEDGES  80000
#define NTOT    90000          // edges + self loops
#define IN_DIM  512
#define H1_DIM  4096
#define H2_DIM  1024
#define ODIM    7
#define MAXDEG  128
#define NEG_SLOPE 0.2f
#define MROWS   10240          // padded M for dot-partial buffers (80 row-panels * 128)
#define NBX1    (H1_DIM / 128) // 32 column blocks in GEMM1

typedef __hip_bfloat16 bf16;
typedef __attribute__((ext_vector_type(8))) short short8;
typedef __attribute__((ext_vector_type(4))) float f32x4;

__device__ inline void unpack_bf2(unsigned u, float& lo, float& hi) {
    union { unsigned i; float f; } a, b;
    a.i = u << 16; b.i = u & 0xffff0000u;
    lo = a.f; hi = b.f;
}

// async global->LDS, 16B per lane; lds ptr must be wave-uniform base (lane*16 added by HW)
#define ASYNC_COPY16(lds, g)                                                              \
    __builtin_amdgcn_global_load_lds((const __attribute__((address_space(1))) void*)(g),  \
                                     (__attribute__((address_space(3))) void*)(lds),      \
                                     16, 0, 0)

// ---------------- merged prep: W1/W2 transpose+fold + bucket build in one launch ----------------
__global__ __launch_bounds__(256) void prep_all(const float* __restrict__ W1,
                                                bf16* __restrict__ W1T,
                                                const float* __restrict__ as1,
                                                const float* __restrict__ ad1,
                                                float* __restrict__ w1s,
                                                float* __restrict__ w1d,
                                                const float* __restrict__ W2,
                                                bf16* __restrict__ W2T,
                                                const float* __restrict__ as2,
                                                const float* __restrict__ ad2,
                                                float* __restrict__ w2s,
                                                float* __restrict__ w2d,
                                                const int* __restrict__ ei,
                                                int* cnt, int* bucket) {
    const int nb1 = (H1_DIM / 32) * (IN_DIM / 32);   // 2048
    const int nb2 = (H2_DIM / 32) * (H1_DIM / 32);   // 4096
    int bid = blockIdx.x;

    if (bid >= nb1 + nb2) {                          // bucket blocks
        int k = (bid - nb1 - nb2) * 256 + threadIdx.x;
        if (k < NTOT) {
            int s, d;
            if (k < NEDGES) { s = ei[k]; d = ei[NEDGES + k]; }
            else            { s = k - NEDGES; d = s; }
            int pos = atomicAdd(&cnt[d], 1);
            if (pos < MAXDEG) bucket[d * MAXDEG + pos] = s;
        }
        return;
    }

    const float *W, *a_s, *a_d; bf16 *WT; float *w_s, *w_d; int R, C, cblocks;
    if (bid < nb1) { W = W1; WT = W1T; a_s = as1; a_d = ad1; w_s = w1s; w_d = w1d;
                     R = IN_DIM; C = H1_DIM; cblocks = H1_DIM / 32; }
    else { bid -= nb1; W = W2; WT = W2T; a_s = as2; a_d = ad2; w_s = w2s; w_d = w2d;
           R = H1_DIM; C = H2_DIM; cblocks = H2_DIM / 32; }
    int c0 = (bid % cblocks) * 32, r0 = (bid / cblocks) * 32;

    __shared__ float t[32][33];
    int x = threadIdx.x & 31, y = threadIdx.x >> 5;   // 32 x 8
    float asv = a_s[c0 + x], adv = a_d[c0 + x];
    #pragma unroll
    for (int dy = 0; dy < 32; dy += 8) {
        float w = W[(size_t)(r0 + y + dy) * C + c0 + x];
        t[y + dy][x] = w;
        float ps = w * asv, pd = w * adv;
        #pragma unroll
        for (int off = 16; off > 0; off >>= 1) {
            ps += __shfl_down(ps, off, 32);
            pd += __shfl_down(pd, off, 32);
        }
        if (x == 0) {
            atomicAdd(&w_s[r0 + y + dy], ps);
            atomicAdd(&w_d[r0 + y + dy], pd);
        }
    }
    __syncthreads();
    #pragma unroll
    for (int dy = 0; dy < 32; dy += 8)
        WT[(size_t)(c0 + y + dy) * R + r0 + x] = __float2bfloat16(t[x][y + dy]);
}

// ---------------- layer-1: node dots on x + bf16 conversion (single x read) ----------------
__global__ __launch_bounds__(128) void dots_cvt1(const float* __restrict__ X,
                                                 const float* __restrict__ w_s,
                                                 const float* __restrict__ w_d,
                                                 float* __restrict__ s_src,
                                                 float* __restrict__ s_dst,
                                                 bf16* __restrict__ XB) {
    int n = blockIdx.x;
    int t = threadIdx.x;                      // 128 threads x float4 = 512
    float4 xv = ((const float4*)(X + (size_t)n * IN_DIM))[t];
    float4 wsv = ((const float4*)w_s)[t];
    float4 wdv = ((const float4*)w_d)[t];
    bf16 o[4] = { __float2bfloat16(xv.x), __float2bfloat16(xv.y),
                  __float2bfloat16(xv.z), __float2bfloat16(xv.w) };
    *(uint2*)(XB + (size_t)n * IN_DIM + 4 * t) = *(uint2*)o;
    float ss = xv.x*wsv.x + xv.y*wsv.y + xv.z*wsv.z + xv.w*wsv.w;
    float sd = xv.x*wdv.x + xv.y*wdv.y + xv.z*wdv.z + xv.w*wdv.w;
    #pragma unroll
    for (int off = 32; off > 0; off >>= 1) {
        ss += __shfl_down(ss, off);
        sd += __shfl_down(sd, off);
    }
    __shared__ float red[2][2];
    int wave = t >> 6;
    if ((t & 63) == 0) { red[0][wave] = ss; red[1][wave] = sd; }
    __syncthreads();
    if (t == 0) {
        s_src[n] = red[0][0] + red[0][1];
        s_dst[n] = red[1][0] + red[1][1];
    }
}

// ---------------- layer-1 aggregate: bf16 gather (F=512) -> bf16 out ----------------
__global__ __launch_bounds__(128) void agg1(const bf16* __restrict__ XB,
                                            const float* __restrict__ s_src,
                                            const float* __restrict__ s_dst,
                                            const int* __restrict__ bucket,
                                            const int* __restrict__ cnt,
                                            bf16* __restrict__ OUT) {
    int n = blockIdx.x;
    int c = min(cnt[n], MAXDEG);
    __shared__ float alpha[MAXDEG];
    __shared__ int   ssrc[MAXDEG];
    if (threadIdx.x < c) {
        int s = bucket[n * MAXDEG + threadIdx.x];
        ssrc[threadIdx.x] = s;
        float e = s_src[s] + s_dst[n];
        alpha[threadIdx.x] = (e > 0.f) ? e : NEG_SLOPE * e;
    }
    __syncthreads();
    if (threadIdx.x == 0) {
        float m = -1e30f;
        for (int j = 0; j < c; ++j) m = fmaxf(m, alpha[j]);
        float s = 0.f;
        for (int j = 0; j < c; ++j) { float ex = __expf(alpha[j] - m); alpha[j] = ex; s += ex; }
        float inv = 1.f / s;
        for (int j = 0; j < c; ++j) alpha[j] *= inv;
    }
    __syncthreads();
    int t = threadIdx.x;                       // 128 threads x 4 bf16 = 512
    float acc[4] = {};
    for (int j = 0; j < c; ++j) {
        float a = alpha[j];
        uint2 raw = ((const uint2*)(XB + (size_t)ssrc[j] * IN_DIM))[t];
        float f0, f1, f2, f3;
        unpack_bf2(raw.x, f0, f1); unpack_bf2(raw.y, f2, f3);
        acc[0] = fmaf(a, f0, acc[0]); acc[1] = fmaf(a, f1, acc[1]);
        acc[2] = fmaf(a, f2, acc[2]); acc[3] = fmaf(a, f3, acc[3]);
    }
    bf16 o[4] = { __float2bfloat16(acc[0]), __float2bfloat16(acc[1]),
                  __float2bfloat16(acc[2]), __float2bfloat16(acc[3]) };
    *(uint2*)(OUT + (size_t)n * IN_DIM + 4 * t) = *(uint2*)o;
}

// ---------------- layer-2 aggregate (+bias+relu) fused with layer-3 projection + dots ----------------
// Lazy reduction of GEMM1's dot partials: thread t<c sums the NBX1 partials for its neighbor
// (L2-hot, 2.6 MB buffer); thread 0 sums pdd for n. Removes the standalone reduce_dots launch.
__global__ __launch_bounds__(128) void agg2_h3(const bf16* __restrict__ H,
                                               const float* __restrict__ pds,
                                               const float* __restrict__ pdd,
                                               const int* __restrict__ bucket,
                                               const int* __restrict__ cnt,
                                               const float* __restrict__ bias,
                                               const float* __restrict__ W3,
                                               const float* __restrict__ as3,
                                               const float* __restrict__ ad3,
                                               float* __restrict__ H3,
                                               float* __restrict__ s3_src,
                                               float* __restrict__ s3_dst) {
    int n = blockIdx.x;
    int c = min(cnt[n], MAXDEG);
    __shared__ float alpha[MAXDEG];
    __shared__ int   ssrc[MAXDEG];
    __shared__ float dstsum;
    int t = threadIdx.x;
    int s_n = -1;
    if (t < c) {
        s_n = bucket[n * MAXDEG + t];
        ssrc[t] = s_n;
    }
    // lazy reduce: e_src for neighbor s_n, dstsum for n
    float esrc = 0.f;
    if (t < c) {
        #pragma unroll
        for (int b = 0; b < NBX1; ++b)
            esrc += pds[(size_t)b * MROWS + s_n];
    }
    if (t == 0) {
        float d = 0.f;
        #pragma unroll
        for (int b = 0; b < NBX1; ++b)
            d += pdd[(size_t)b * MROWS + n];
        dstsum = d;
    }
    __syncthreads();
    if (t < c) {
        float e = esrc + dstsum;
        alpha[t] = (e > 0.f) ? e : NEG_SLOPE * e;
    }
    __syncthreads();
    if (t == 0) {
        float m = -1e30f;
        for (int j = 0; j < c; ++j) m = fmaxf(m, alpha[j]);
        float s = 0.f;
        for (int j = 0; j < c; ++j) { float ex = __expf(alpha[j] - m); alpha[j] = ex; s += ex; }
        float inv = 1.f / s;
        for (int j = 0; j < c; ++j) alpha[j] *= inv;
    }
    __syncthreads();
    float acc[8] = {};
    for (int j = 0; j < c; ++j) {
        float a = alpha[j];
        uint4 raw = ((const uint4*)(H + (size_t)ssrc[j] * H2_DIM))[t];
        float f0, f1, f2, f3, f4, f5, f6, f7;
        unpack_bf2(raw.x, f0, f1); unpack_bf2(raw.y, f2, f3);
        unpack_bf2(raw.z, f4, f5); unpack_bf2(raw.w, f6, f7);
        acc[0] = fmaf(a, f0, acc[0]); acc[1] = fmaf(a, f1, acc[1]);
        acc[2] = fmaf(a, f2, acc[2]); acc[3] = fmaf(a, f3, acc[3]);
        acc[4] = fmaf(a, f4, acc[4]); acc[5] = fmaf(a, f5, acc[5]);
        acc[6] = fmaf(a, f6, acc[6]); acc[7] = fmaf(a, f7, acc[7]);
    }
    // x3 values (relu(acc+bias)) -> partial h3 via W3 rows 8t..8t+7
    float p[ODIM] = {};
    #pragma unroll
    for (int k = 0; k < 8; ++k) {
        float v = fmaxf(acc[k] + bias[8 * t + k], 0.f);
        const float* wrow = W3 + (size_t)(8 * t + k) * ODIM;
        #pragma unroll
        for (int o = 0; o < ODIM; ++o)
            p[o] = fmaf(v, wrow[o], p[o]);
    }
    #pragma unroll
    for (int o = 0; o < ODIM; ++o)
        #pragma unroll
        for (int off = 32; off > 0; off >>= 1)
            p[o] += __shfl_down(p[o], off);
    __shared__ float red[2][ODIM];
    int wave = t >> 6;
    if ((t & 63) == 0)
        #pragma unroll
        for (int o = 0; o < ODIM; ++o) red[wave][o] = p[o];
    __syncthreads();
    if (t == 0) {
        float ss = 0.f, sd = 0.f;
        #pragma unroll
        for (int o = 0; o < ODIM; ++o) {
            float v = red[0][o] + red[1][o];
            H3[n * ODIM + o] = v;
            ss = fmaf(v, as3[o], ss);
            sd = fmaf(v, ad3[o], sd);
        }
        s3_src[n] = ss; s3_dst[n] = sd;
    }
}

// ---------------- bf16 MFMA GEMM (gemm_bt): C[M,N] = A[M,K] @ BT[N,K]^T ----------------
// 16x16x32 fragments. TM=TN=128, 4 waves. XCD-affine block swizzle (R7). XOR k-chunk swizzle.
// PIPE=false: 2-barrier BK=64 (short K, R8); PIPE=true: single-barrier BK=32 dbuf (long K, R8).
// FUSEDOTS: dot partials in LDS -> one coalesced store per row into [NBX1][MROWS] partials.
template<bool BIASRELU, bool FUSEDOTS, bool PIPE>
__global__ __launch_bounds__(256) void gemm_mfma(const bf16* __restrict__ A,
                                                 const bf16* __restrict__ BT,
                                                 const float* __restrict__ bias,
                                                 const float* __restrict__ w_s,
                                                 const float* __restrict__ w_d,
                                                 float* __restrict__ s_src,
                                                 float* __restrict__ s_dst,
                                                 bf16* __restrict__ C,
                                                 int M, int N, int K) {
    constexpr int TM = 128, TN = 128, NI = 4, NJ = 4;
    __shared__ alignas(16) bf16 As[2][TM][32];
    __shared__ alignas(16) bf16 Bs[2][TN][32];
    __shared__ float pd_s[FUSEDOTS ? TM : 1];
    __shared__ float pd_d[FUSEDOTS ? TM : 1];
    const int tid  = threadIdx.x;
    const int wave = tid >> 6;
    const int lane = tid & 63;

    const int gx = gridDim.x;
    const int j  = blockIdx.y * gx + blockIdx.x;
    const int band = j / (8 * gx);
    const int r8   = j - band * (8 * gx);
    const int by = (r8 & 7) + 8 * band;
    const int bx = r8 >> 3;
    const int row0 = by * TM;
    const int col0 = bx * TN;
    if (row0 >= M) return;

    if constexpr (FUSEDOTS) {
        if (tid < TM) { pd_s[tid] = 0.f; pd_d[tid] = 0.f; }
    }

    const int wr0 = (wave >> 1) * 64;
    const int wc0 = (wave & 1) * 64;

    const int srow  = tid >> 2;
    const int skoff = ((tid & 3) ^ (srow & 3)) * 8;
    const bf16* a0 = A + (size_t)min(row0 + srow, M - 1) * K + skoff;
    const bf16* a1 = A + (size_t)min(row0 + 64 + srow, M - 1) * K + skoff;
    const bf16* b0 = BT + (size_t)(col0 + srow) * K + skoff;
    const bf16* b1 = BT + (size_t)(col0 + 64 + srow) * K + skoff;

    f32x4 acc[NI][NJ] = {};
    const int fRow  = lane & 15;
    const int fKoff = ((lane >> 4) ^ (fRow & 3)) * 8;

    if constexpr (PIPE) {
        const int NIT = K >> 5;
        ASYNC_COPY16(&As[0][wave * 16][0],      a0);
        ASYNC_COPY16(&As[0][64 + wave * 16][0], a1);
        ASYNC_COPY16(&Bs[0][wave * 16][0],      b0);
        ASYNC_COPY16(&Bs[0][64 + wave * 16][0], b1);
        __syncthreads();
        for (int it = 0; it < NIT; ++it) {
            const int cb = it & 1, nb = cb ^ 1;
            if (it + 1 < NIT) {
                const int ko = (it + 1) << 5;
                ASYNC_COPY16(&As[nb][wave * 16][0],      a0 + ko);
                ASYNC_COPY16(&As[nb][64 + wave * 16][0], a1 + ko);
                ASYNC_COPY16(&Bs[nb][wave * 16][0],      b0 + ko);
                ASYNC_COPY16(&Bs[nb][64 + wave * 16][0], b1 + ko);
            }
            short8 af[NI], bfr[NJ];
            #pragma unroll
            for (int i = 0; i < NI; ++i)
                af[i] = *(const short8*)&As[cb][wr0 + i * 16 + fRow][fKoff];
            #pragma unroll
            for (int jj = 0; jj < NJ; ++jj)
                bfr[jj] = *(const short8*)&Bs[cb][wc0 + jj * 16 + fRow][fKoff];
            #pragma unroll
            for (int i = 0; i < NI; ++i)
                #pragma unroll
                for (int jj = 0; jj < NJ; ++jj)
                    acc[i][jj] = __builtin_amdgcn_mfma_f32_16x16x32_bf16(af[i], bfr[jj], acc[i][jj], 0, 0, 0);
            __syncthreads();
        }
    } else {
        for (int k0 = 0; k0 < K; k0 += 64) {
            #pragma unroll
            for (int h = 0; h < 2; ++h) {
                ASYNC_COPY16(&As[h][wave * 16][0],      a0 + k0 + h * 32);
                ASYNC_COPY16(&As[h][64 + wave * 16][0], a1 + k0 + h * 32);
                ASYNC_COPY16(&Bs[h][wave * 16][0],      b0 + k0 + h * 32);
                ASYNC_COPY16(&Bs[h][64 + wave * 16][0], b1 + k0 + h * 32);
            }
            __syncthreads();
            #pragma unroll
            for (int h = 0; h < 2; ++h) {
                short8 af[NI], bfr[NJ];
                #pragma unroll
                for (int i = 0; i < NI; ++i)
                    af[i] = *(const short8*)&As[h][wr0 + i * 16 + fRow][fKoff];
                #pragma unroll
                for (int jj = 0; jj < NJ; ++jj)
                    bfr[jj] = *(const short8*)&Bs[h][wc0 + jj * 16 + fRow][fKoff];
                #pragma unroll
                for (int i = 0; i < NI; ++i)
                    #pragma unroll
                    for (int jj = 0; jj < NJ; ++jj)
                        acc[i][jj] = __builtin_amdgcn_mfma_f32_16x16x32_bf16(af[i], bfr[jj], acc[i][jj], 0, 0, 0);
            }
            __syncthreads();
        }
    }

    // epilogue: C/D layout col=lane&15, row=(lane>>4)*4+reg [m89/m91]
    const int crow = (lane >> 4) * 4;
    const int ccol = lane & 15;
    #pragma unroll
    for (int i = 0; i < NI; ++i) {
        #pragma unroll
        for (int r = 0; r < 4; ++r) {
            int gm = row0 + wr0 + i * 16 + crow + r;
            float vss = 0.f, vsd = 0.f;
            if (gm < M) {
                #pragma unroll
                for (int jj = 0; jj < NJ; ++jj) {
                    int gn = col0 + wc0 + jj * 16 + ccol;
                    float v = acc[i][jj][r];
                    if (BIASRELU) v = fmaxf(v + bias[gn], 0.f);
                    C[(size_t)gm * N + gn] = __float2bfloat16(v);
                    if (FUSEDOTS) {
                        vss = fmaf(v, w_s[gn], vss);
                        vsd = fmaf(v, w_d[gn], vsd);
                    }
                }
            }
            if (FUSEDOTS) {
                #pragma unroll
                for (int m2 = 1; m2 < 16; m2 <<= 1) {
                    vss += __shfl_xor(vss, m2, 16);
                    vsd += __shfl_xor(vsd, m2, 16);
                }
                if ((lane & 15) == 0) {
                    atomicAdd(&pd_s[wr0 + i * 16 + crow + r], vss);   // LDS atomic (cheap)
                    atomicAdd(&pd_d[wr0 + i * 16 + crow + r], vsd);
                }
            }
        }
    }
    if constexpr (FUSEDOTS) {
        __syncthreads();
        if (tid < TM) {
            s_src[(size_t)bx * MROWS + row0 + tid] = pd_s[tid];
            s_dst[(size_t)bx * MROWS + row0 + tid] = pd_d[tid];
        }
    }
}

// ---------------- layer3 aggregate + bias + log_softmax ----------------
__global__ __launch_bounds__(128) void aggregate3(const float* __restrict__ H3,
                                                  const float* __restrict__ s_src,
                                                  const float* __restrict__ s_dst,
                                                  const int* __restrict__ bucket,
                                                  const int* __restrict__ cnt,
                                                  const float* __restrict__ b3,
                                                  float* __restrict__ out) {
    int n = blockIdx.x;
    int c = min(cnt[n], MAXDEG);
    __shared__ float alpha[MAXDEG];
    __shared__ int   ssrc[MAXDEG];
    __shared__ float o[ODIM];
    if (threadIdx.x < c) {
        int s = bucket[n * MAXDEG + threadIdx.x];
        ssrc[threadIdx.x] = s;
        float e = s_src[s] + s_dst[n];
        alpha[threadIdx.x] = (e > 0.f) ? e : NEG_SLOPE * e;
    }
    __syncthreads();
    if (threadIdx.x == 0) {
        float m = -1e30f;
        for (int j = 0; j < c; ++j) m = fmaxf(m, alpha[j]);
        float s = 0.f;
        for (int j = 0; j < c; ++j) { float ex = __expf(alpha[j] - m); alpha[j] = ex; s += ex; }
        float inv = 1.f / s;
        for (int j = 0; j < c; ++j) alpha[j] *= inv;
    }
    __syncthreads();
    if (threadIdx.x < ODIM) {
        float acc = 0.f;
        for (int j = 0; j < c; ++j)
            acc = fmaf(alpha[j], H3[ssrc[j] * ODIM + threadIdx.x], acc);
        o[threadIdx.x] = acc + b3[threadIdx.x];
    }
    __syncthreads();
    if (threadIdx.x == 0) {
        float m = o[0];
        for (int k = 1; k < ODIM; ++k) m = fmaxf(m, o[k]);
        float s = 0.f;
        for (int k = 0; k < ODIM; ++k) s += __expf(o[k] - m);
        float lse = m + logf(s);
        for (int k = 0; k < ODIM; ++k) out[n * ODIM + k] = o[k] - lse;
    }
}

// ---------------- host launch ----------------
extern "C" void kernel_launch(void* const* d_in, const int* in_sizes, int n_in,
                              void* d_out, int out_size, void* d_ws, size_t ws_size,
                              hipStream_t stream) {
    const float* x   = (const float*)d_in[0];
    const int*   ei  = (const int*)  d_in[1];
    const float* W1  = (const float*)d_in[2];
    const float* as1 = (const float*)d_in[3];
    const float* ad1 = (const float*)d_in[4];
    const float* b1  = (const float*)d_in[5];
    const float* W2  = (const float*)d_in[6];
    const float* as2 = (const float*)d_in[7];
    const float* ad2 = (const float*)d_in[8];
    const float* b2  = (const float*)d_in[9];
    const float* W3  = (const float*)d_in[10];
    const float* as3 = (const float*)d_in[11];
    const float* ad3 = (const float*)d_in[12];
    const float* b3  = (const float*)d_in[13];
    float* outp = (float*)d_out;

    // workspace layout with aliasing (~140 MB); w1s..w2d and cnt adjacent -> ONE memset
    char* p = (char*)d_ws;
    bf16*  x2     = (bf16*)p;   p += (size_t)NNODES * H1_DIM * sizeof(bf16);   // 81.92 MB
    bf16*  r2     = (bf16*)p;   p += (size_t)NNODES * H2_DIM * sizeof(bf16);   // 20.48 MB
    bf16*  r3     = (bf16*)p;   p += (size_t)NNODES * H2_DIM * sizeof(bf16);   // 20.48 MB
    bf16*  W2T    = (bf16*)p;   p += (size_t)H2_DIM * H1_DIM * sizeof(bf16);   // 8.39 MB
    float* pds    = (float*)p;  p += (size_t)NBX1 * MROWS * sizeof(float);     // 1.31 MB
    float* pdd    = (float*)p;  p += (size_t)NBX1 * MROWS * sizeof(float);     // 1.31 MB
    float* h3     = (float*)p;  p += (size_t)NNODES * ODIM * sizeof(float);
    float* ssrc   = (float*)p;  p += NNODES * sizeof(float);
    float* sdst   = (float*)p;  p += NNODES * sizeof(float);
    float* ssrc3  = (float*)p;  p += NNODES * sizeof(float);
    float* sdst3  = (float*)p;  p += NNODES * sizeof(float);
    float* w1s    = (float*)p;  p += IN_DIM * sizeof(float);                   // zero-group start
    float* w1d    = (float*)p;  p += IN_DIM * sizeof(float);
    float* w2s    = (float*)p;  p += H1_DIM * sizeof(float);
    float* w2d    = (float*)p;  p += H1_DIM * sizeof(float);
    int*   cnt    = (int*)p;    p += NNODES * sizeof(int);                     // zero-group end
    int*   bucket = (int*)p;    p += (size_t)NNODES * MAXDEG * sizeof(int);    // 5.12 MB
    size_t required = (size_t)(p - (char*)d_ws);
    if (ws_size < required) return;

    bf16* xb    = x2;              // [10000][512] bf16 copy of x (dead before GEMM1 writes x2)
    bf16* aggxb = r2;              // [10000][512]  (dead after GEMM1)
    bf16* h2    = r2;              // [10000][1024] (written by GEMM2)
    bf16* W1T   = r3;              // [4096][512]   (dead after GEMM1)

    // one memset for w1s..w2d (float zeros) + cnt (int zeros): contiguous all-zero bytes
    hipMemsetAsync(w1s, 0, (2 * IN_DIM + 2 * H1_DIM) * sizeof(float) + NNODES * sizeof(int), stream);

    // ---- merged prep: both transposes + attention folds + edge bucketing (one launch) ----
    {
        int nb1 = (H1_DIM / 32) * (IN_DIM / 32);     // 2048
        int nb2 = (H2_DIM / 32) * (H1_DIM / 32);     // 4096
        int nbB = (NTOT + 255) / 256;                // 352
        prep_all<<<nb1 + nb2 + nbB, 256, 0, stream>>>(W1, W1T, as1, ad1, w1s, w1d,
                                                      W2, W2T, as2, ad2, w2s, w2d,
                                                      ei, cnt, bucket);
    }

    // ---- layer 1: dots+cvt on x (one read), bf16 gather aggregate ----
    dots_cvt1<<<NNODES, 128, 0, stream>>>(x, w1s, w1d, ssrc, sdst, xb);
    agg1<<<NNODES, 128, 0, stream>>>(xb, ssrc, sdst, bucket, cnt, aggxb);

    // padded row-panel count (multiple of 8 for the XCD swizzle)
    const int nRowPad = ((((NNODES + 127) / 128) + 7) / 8) * 8;   // 80

    // ---- GEMM1 (+bias+relu) with fused layer-2 dot partials: 2-barrier BK=64 (short K) ----
    {
        dim3 g(H1_DIM / 128, nRowPad);
        gemm_mfma<true, true, false><<<g, 256, 0, stream>>>(aggxb, W1T, b1, w2s, w2d,
                                                            pds, pdd, x2, NNODES, H1_DIM, IN_DIM);
    }

    // ---- GEMM2: single-barrier BK=32 dbuf (long K) ----
    {
        dim3 g(H2_DIM / 128, nRowPad);
        gemm_mfma<false, false, true><<<g, 256, 0, stream>>>(x2, W2T, nullptr, nullptr, nullptr,
                                                             nullptr, nullptr, h2, NNODES, H2_DIM, H1_DIM);
    }

    // ---- layer-2 aggregate (lazy partial reduce) fused with layer-3 projection + dots ----
    agg2_h3<<<NNODES, 128, 0, stream>>>(h2, pds, pdd, bucket, cnt, b2,
                                        W3, as3, ad3, h3, ssrc3, sdst3);

    // ---- layer 3 aggregate + log_softmax ----
    aggregate3<<<NNODES, 128, 0, stream>>>(h3, ssrc3, sdst3, bucket, cnt, b3, outp);
}